// Round 5
// baseline (46429.572 us; speedup 1.0000x reference)
//
#include <hip/hip_runtime.h>

#define LSEQ 8128
#define NB 8
#define CORR_CAP 8192
#define GST 260          // gbuf row stride (shorts)
#define HST 264          // hT row stride (shorts)
#define RINGSZ 512
#define FLAG_R0 0        // dword offsets into flags area (spread across lines)
#define FLAG_H0 32
#define FLAG_H1 64
#define PROG_R1 96

typedef __attribute__((ext_vector_type(8))) short short8;
typedef __attribute__((ext_vector_type(4))) float float4e;

#define MFMA16(a, b, c) __builtin_amdgcn_mfma_f32_16x16x32_bf16((a), (b), (c), 0, 0, 0)

// ---- workspace layout (bytes), all 4 KB aligned ----
#define WS_P      4096ul
#define WS_AEE    528384ul      // P + 524288
#define WS_VPN    536576ul      // bf16 [8128][1024] = 16646144
#define WS_EIDX   17182720ul    // 65024*4 -> pad 262144
#define WS_CORR   17444864ul    // bf16 [8192][1024] = 16777216
#define WS_URING  34222080ul    // bf16 ring [512][8][1024] = 8388608
#define WS_H0     42610688ul    // bf16 [8129][8][256] = 33296384
#define WS_H1     75907072ul    // same
// end ~109.2 MB

static __device__ __forceinline__ unsigned short f2bf(float f) {
  unsigned u = __float_as_uint(f);
  return (unsigned short)((u + 0x7fffu + ((u >> 16) & 1u)) >> 16);  // RNE
}
static __device__ __forceinline__ float b2f(unsigned short u) {
  return __uint_as_float(((unsigned)u) << 16);
}
static __device__ __forceinline__ short8 pack8f(const float* __restrict__ p) {
  short8 r;
#pragma unroll
  for (int i = 0; i < 8; ++i) r[i] = (short)f2bf(p[i]);
  return r;
}
static __device__ __forceinline__ unsigned aload(const unsigned* p) {
  return __hip_atomic_load(p, __ATOMIC_RELAXED, __HIP_MEMORY_SCOPE_AGENT);
}
static __device__ __forceinline__ void astore(unsigned* p, unsigned v) {
  __hip_atomic_store(p, v, __ATOMIC_RELAXED, __HIP_MEMORY_SCOPE_AGENT);
}
static __device__ __forceinline__ void fencev() {
  asm volatile("s_waitcnt vmcnt(0)" ::: "memory");
}
static __device__ __forceinline__ void cbar() { asm volatile("" ::: "memory"); }
// barrier that drains LDS only (NOT vmcnt) — keeps astores fire-and-forget
static __device__ __forceinline__ void barrier_lgkm() {
  asm volatile("s_waitcnt lgkmcnt(0)\ns_barrier" ::: "memory");
}
static __device__ __forceinline__ float sigf(float x) { return 1.f / (1.f + __expf(-x)); }
static __device__ __forceinline__ float tanhf2(float x) { return 2.f / (1.f + __expf(-2.f * x)) - 1.f; }

// ---- P = W_ih0[:,128:192] @ ew_W2   [1024][128] ----
__global__ void k_prep_P(const float* __restrict__ Wih0, const float* __restrict__ ewW2,
                         float* __restrict__ P) {
  int idx = blockIdx.x * 256 + threadIdx.x;
  int g = idx >> 7, k = idx & 127;
  const float* wr = Wih0 + (size_t)g * 320 + 128;
  float s = 0.f;
#pragma unroll 8
  for (int j = 0; j < 64; ++j) s += wr[j] * ewW2[j * 128 + k];
  P[idx] = s;
}

__global__ void k_prep_aee_init(const float* __restrict__ Wih0, const float* __restrict__ ee,
                                const float* __restrict__ b1, const float* __restrict__ b2,
                                const float* __restrict__ P, const float* __restrict__ inith,
                                float* __restrict__ aee, unsigned short* __restrict__ h0u,
                                unsigned short* __restrict__ h1u) {
  int idx = blockIdx.x * 256 + threadIdx.x;  // < 2048
  int s = idx >> 10, g = idx & 1023;
  const float* wr = Wih0 + (size_t)g * 320;
  float a = 0.f;
#pragma unroll 8
  for (int i = 0; i < 128; ++i) a += wr[i] * ee[s * 128 + i];
#pragma unroll 8
  for (int j = 0; j < 64; ++j) a += wr[128 + j] * b2[j];
  const float* pr = P + (size_t)g * 128;
#pragma unroll 8
  for (int k = 0; k < 128; ++k) a += pr[k] * fmaxf(b1[k], 0.f);
  aee[s * 1024 + g] = a;
  unsigned short hv = f2bf(inith[idx & 127]);
  h0u[idx] = hv;
  h1u[idx] = hv;
}

// vpn bf16: vpn[t][g] = Wih0[:,192:320]@[pe;ne] + aee0
__global__ void k_prep_vpn(const float* __restrict__ Wih0, const float* __restrict__ nemb,
                           const float* __restrict__ aee, unsigned short* __restrict__ vpn) {
  __shared__ float pn[128];
  int t = blockIdx.x, tid = threadIdx.x;
  if (tid < 32) {
    float div = expf(-9.2103403719761836f * (float)(2 * tid) / 64.f);
    float ang = (float)t * div;
    pn[2 * tid] = sinf(ang);
    pn[2 * tid + 1] = cosf(ang);
  } else if (tid < 96) {
    int r = (int)((1.f + sqrtf(8.f * (float)t + 1.f)) * 0.5f);
    while (r * (r + 1) / 2 <= t) ++r;
    while (r * (r - 1) / 2 > t) --r;
    pn[64 + (tid - 32)] = nemb[r * 64 + (tid - 32)];
  }
  __syncthreads();
#pragma unroll
  for (int rr = 0; rr < 4; ++rr) {
    int row = rr * 256 + tid;
    const float* wr = Wih0 + (size_t)row * 320 + 192;
    float s = 0.f;
#pragma unroll 8
    for (int i = 0; i < 128; ++i) s += wr[i] * pn[i];
    vpn[(size_t)t * 1024 + row] = f2bf(s + aee[row]);
  }
}

__global__ void k_prep_eidx(const float* __restrict__ xadj, int* __restrict__ eidx,
                            unsigned* __restrict__ counter) {
  int idx = blockIdx.x * 256 + threadIdx.x;
  if (idx >= NB * LSEQ) return;
  int t = idx % LSEQ;
  int e = -1;
  if (t > 0 && xadj[idx - 1] > 0.f) {
    e = (int)atomicAdd(counter, 1u);
    if (e >= CORR_CAP) e = -1;
  }
  eidx[idx] = e;
}

__global__ void k_prep_corr(const float* __restrict__ xadj, const float* __restrict__ w1,
                            const float* __restrict__ b1, const float* __restrict__ P,
                            const float* __restrict__ aee, const int* __restrict__ eidx,
                            unsigned short* __restrict__ corr) {
  __shared__ float rh[128];
  int bid = blockIdx.x;
  int e = eidx[bid];
  if (e < 0) return;
  int tid = threadIdx.x;
  float wt = xadj[bid - 1];
  if (tid < 128) {
    float bb = b1[tid];
    rh[tid] = fmaxf(wt * w1[tid] + bb, 0.f) - fmaxf(bb, 0.f);
  }
  __syncthreads();
#pragma unroll
  for (int rr = 0; rr < 4; ++rr) {
    int row = rr * 256 + tid;
    const float* pr = P + (size_t)row * 128;
    float s = 0.f;
#pragma unroll 8
    for (int k = 0; k < 128; ++k) s += pr[k] * rh[k];
    corr[(size_t)e * 1024 + row] = f2bf(s + aee[1024 + row] - aee[row]);
  }
}

// ============ persistent single-CU recurrence LSTM ============
// WG0 = layer0 (free-running), WG1 = layer1, WG2/3 = u = Wih1@h0 producers.
// All per-step recurrence dependencies stay inside one CU (LDS + regs).
static __device__ __forceinline__ void writeg(unsigned short* gbuf, int lm, int mt, int lk,
                                              float4e a) {
  int G = mt >> 4, jb = (mt & 15) * 16 + lk * 4;
  unsigned p0 = (unsigned)f2bf(a[0]) | ((unsigned)f2bf(a[1]) << 16);
  unsigned p1 = (unsigned)f2bf(a[2]) | ((unsigned)f2bf(a[3]) << 16);
  *(uint2*)&gbuf[(lm * 4 + G) * GST + jb] = make_uint2(p0, p1);
}

template <int LAYER>
static __device__ __forceinline__ void recur(
    const float* __restrict__ Wrec, const unsigned short* __restrict__ vpn,
    const int* __restrict__ eidx, const unsigned short* __restrict__ corr,
    const unsigned* __restrict__ uring, const float* __restrict__ inith,
    const float* __restrict__ initc, unsigned* flags, unsigned* hout,
    short* wlds, unsigned short* hT, unsigned short* gbuf, int tid) {
  const int wv = tid >> 6, l = tid & 63, lm = l & 15, lk = l >> 4;
  const int b = wv, j0 = l * 4;
  unsigned budget = 20000000u;

  for (int i = tid; i < 16 * HST; i += 512) hT[i] = 0;
  __syncthreads();
  {
    unsigned h01 = (unsigned)f2bf(inith[j0 & 127]) | ((unsigned)f2bf(inith[(j0 + 1) & 127]) << 16);
    unsigned h23 = (unsigned)f2bf(inith[(j0 + 2) & 127]) | ((unsigned)f2bf(inith[(j0 + 3) & 127]) << 16);
    *(uint2*)&hT[b * HST + j0] = make_uint2(h01, h23);
  }
  float c[4];
#pragma unroll
  for (int r = 0; r < 4; ++r) c[r] = initc[(j0 + r) & 127];

  // weights: per wave 8 m-tiles; tiles 0-5 in regs (192 VGPR), 6-7 in LDS
  short8 wf[6][8];
#pragma unroll
  for (int tt = 0; tt < 6; ++tt) {
    int row = (wv * 8 + tt) * 16 + lm;
#pragma unroll
    for (int ks = 0; ks < 8; ++ks)
      wf[tt][ks] = pack8f(Wrec + (size_t)row * 256 + ks * 32 + lk * 8);
  }
#pragma unroll
  for (int tt = 0; tt < 2; ++tt) {
    int row = (wv * 8 + 6 + tt) * 16 + lm, s = wv * 2 + tt;
#pragma unroll
    for (int ks = 0; ks < 8; ++ks) {
      short8 w = pack8f(Wrec + (size_t)row * 256 + ks * 32 + lk * 8);
      *(short8*)&wlds[((s * 8 + ks) * 64 + l) * 8] = w;
    }
  }
  __syncthreads();

  unsigned Tc0 = 0, Tc1 = 0;
  for (int t = 0; t < LSEQ; ++t) {
    // ---- inputs (consumed in update phase; latency hidden behind MFMAs) ----
    uint2 vv[4], cv[4], uv[4];
    if (LAYER == 0) {
      int e = eidx[b * LSEQ + t];
#pragma unroll
      for (int G = 0; G < 4; ++G)
        vv[G] = *(const uint2*)(vpn + (size_t)t * 1024 + G * 256 + j0);
      if (e >= 0) {
#pragma unroll
        for (int G = 0; G < 4; ++G)
          cv[G] = *(const uint2*)(corr + (size_t)e * 1024 + G * 256 + j0);
      } else {
#pragma unroll
        for (int G = 0; G < 4; ++G) cv[G] = make_uint2(0u, 0u);
      }
    } else {
      unsigned Tm = (Tc0 < Tc1) ? Tc0 : Tc1;
      while (Tm < (unsigned)(t + 1)) {
        Tc0 = aload(flags + FLAG_H0);
        Tc1 = aload(flags + FLAG_H1);
        Tm = (Tc0 < Tc1) ? Tc0 : Tc1;
        if (--budget == 0) break;
        asm volatile("s_sleep 1");
      }
      cbar();
      const unsigned* ub = uring + (size_t)(t & (RINGSZ - 1)) * 4096 + b * 512 + (j0 >> 1);
#pragma unroll
      for (int G = 0; G < 4; ++G) {
        uv[G].x = aload(ub + G * 128);
        uv[G].y = aload(ub + G * 128 + 1);
      }
    }
    // ---- MFMA phase: gates_rec = Wrec @ h(t-1) ----
    short8 bfr[8];
#pragma unroll
    for (int ks = 0; ks < 8; ++ks)
      bfr[ks] = *(const short8*)(hT + lm * HST + ks * 32 + lk * 8);
#pragma unroll
    for (int tp = 0; tp < 3; ++tp) {
      float4e a0 = {0.f, 0.f, 0.f, 0.f}, a1 = {0.f, 0.f, 0.f, 0.f};
#pragma unroll
      for (int ks = 0; ks < 8; ++ks) {
        a0 = MFMA16(wf[2 * tp][ks], bfr[ks], a0);
        a1 = MFMA16(wf[2 * tp + 1][ks], bfr[ks], a1);
      }
      if (lm < 8) {
        writeg(gbuf, lm, wv * 8 + 2 * tp, lk, a0);
        writeg(gbuf, lm, wv * 8 + 2 * tp + 1, lk, a1);
      }
    }
    {
      float4e a0 = {0.f, 0.f, 0.f, 0.f}, a1 = {0.f, 0.f, 0.f, 0.f};
      int s0 = wv * 2, s1 = s0 + 1;
#pragma unroll
      for (int ks = 0; ks < 8; ++ks) {
        short8 w0 = *(const short8*)&wlds[((s0 * 8 + ks) * 64 + l) * 8];
        short8 w1 = *(const short8*)&wlds[((s1 * 8 + ks) * 64 + l) * 8];
        a0 = MFMA16(w0, bfr[ks], a0);
        a1 = MFMA16(w1, bfr[ks], a1);
      }
      if (lm < 8) {
        writeg(gbuf, lm, wv * 8 + 6, lk, a0);
        writeg(gbuf, lm, wv * 8 + 7, lk, a1);
      }
    }
    barrier_lgkm();
    // ---- update phase: thread owns (b=wv, j0..j0+3) ----
    {
      float gt[4][4];
#pragma unroll
      for (int G = 0; G < 4; ++G) {
        uint2 gv = *(const uint2*)&gbuf[(b * 4 + G) * GST + j0];
        float m0 = b2f((unsigned short)(gv.x & 0xffff));
        float m1 = b2f((unsigned short)(gv.x >> 16));
        float m2 = b2f((unsigned short)(gv.y & 0xffff));
        float m3 = b2f((unsigned short)(gv.y >> 16));
        if (LAYER == 0) {
          m0 += b2f((unsigned short)(vv[G].x & 0xffff)) + b2f((unsigned short)(cv[G].x & 0xffff));
          m1 += b2f((unsigned short)(vv[G].x >> 16)) + b2f((unsigned short)(cv[G].x >> 16));
          m2 += b2f((unsigned short)(vv[G].y & 0xffff)) + b2f((unsigned short)(cv[G].y & 0xffff));
          m3 += b2f((unsigned short)(vv[G].y >> 16)) + b2f((unsigned short)(cv[G].y >> 16));
        } else {
          m0 += b2f((unsigned short)(uv[G].x & 0xffff));
          m1 += b2f((unsigned short)(uv[G].x >> 16));
          m2 += b2f((unsigned short)(uv[G].y & 0xffff));
          m3 += b2f((unsigned short)(uv[G].y >> 16));
        }
        gt[G][0] = m0; gt[G][1] = m1; gt[G][2] = m2; gt[G][3] = m3;
      }
      float hv[4];
#pragma unroll
      for (int r = 0; r < 4; ++r) {
        float cn = sigf(gt[1][r]) * c[r] + sigf(gt[0][r]) * tanhf2(gt[2][r]);
        c[r] = cn;
        hv[r] = sigf(gt[3][r]) * tanhf2(cn);
      }
      unsigned h01 = (unsigned)f2bf(hv[0]) | ((unsigned)f2bf(hv[1]) << 16);
      unsigned h23 = (unsigned)f2bf(hv[2]) | ((unsigned)f2bf(hv[3]) << 16);
      *(uint2*)&hT[b * HST + j0] = make_uint2(h01, h23);
      unsigned* hp = hout + (size_t)(t + 1) * 1024 + b * 128 + (j0 >> 1);
      astore(hp, h01);
      astore(hp + 1, h23);
    }
    barrier_lgkm();
    if (LAYER == 0) {
      if ((t & 7) == 7) {
        fencev();          // each wave drains its astores
        __syncthreads();   // all waves drained
        if (tid == 0) astore(flags + FLAG_R0, (unsigned)(t + 1));
      }
    } else {
      if ((t & 63) == 63 && tid == 0) astore(flags + PROG_R1, (unsigned)(t + 1));
    }
  }
}

static __device__ __forceinline__ void uprod(
    int hid, const float* __restrict__ Wih1, unsigned* flags,
    const unsigned* __restrict__ h0w, unsigned* uring, unsigned short* hB, int tid) {
  const int wv = tid >> 6, l = tid & 63, lm = l & 15, lk = l >> 4;
  unsigned budget = 20000000u;
  for (int i = tid; i < 16 * HST; i += 512) hB[i] = 0;
  short8 wf[4][8];
#pragma unroll
  for (int tt = 0; tt < 4; ++tt) {
    int row = hid * 512 + (wv * 4 + tt) * 16 + lm;
#pragma unroll
    for (int ks = 0; ks < 8; ++ks)
      wf[tt][ks] = pack8f(Wih1 + (size_t)row * 256 + ks * 32 + lk * 8);
  }
  __syncthreads();
  unsigned Fc = 0, Pc = 0;
  for (int t = 0; t < LSEQ; ++t) {
    while (Fc < (unsigned)(t + 1)) {
      Fc = aload(flags + FLAG_R0);
      if (--budget == 0) break;
      asm volatile("s_sleep 1");
    }
    while ((unsigned)t >= Pc + 448u) {  // ring back-pressure
      Pc = aload(flags + PROG_R1);
      if (--budget == 0) break;
      asm volatile("s_sleep 1");
    }
    cbar();
    // h0(t) lives at slot t+1; written via LLC-direct atomics, lines never cached
    // on this XCD since launch -> plain vector load is coherent.
    uint2 hw = ((const uint2*)(h0w + (size_t)(t + 1) * 1024))[tid];
    int d = tid * 2;
    *(uint2*)((unsigned*)hB + (d >> 7) * (HST / 2) + (d & 127)) = hw;
    barrier_lgkm();
    short8 bfr[8];
#pragma unroll
    for (int ks = 0; ks < 8; ++ks)
      bfr[ks] = *(const short8*)(hB + lm * HST + ks * 32 + lk * 8);
    int slot = t & (RINGSZ - 1);
#pragma unroll
    for (int tp = 0; tp < 2; ++tp) {
      float4e a0 = {0.f, 0.f, 0.f, 0.f}, a1 = {0.f, 0.f, 0.f, 0.f};
#pragma unroll
      for (int ks = 0; ks < 8; ++ks) {
        a0 = MFMA16(wf[2 * tp][ks], bfr[ks], a0);
        a1 = MFMA16(wf[2 * tp + 1][ks], bfr[ks], a1);
      }
      if (lm < 8) {
#pragma unroll
        for (int q = 0; q < 2; ++q) {
          float4e a = q ? a1 : a0;
          int g0 = hid * 512 + (wv * 4 + 2 * tp + q) * 16 + lk * 4;
          unsigned p0 = (unsigned)f2bf(a[0]) | ((unsigned)f2bf(a[1]) << 16);
          unsigned p1 = (unsigned)f2bf(a[2]) | ((unsigned)f2bf(a[3]) << 16);
          unsigned* up = uring + (size_t)slot * 4096 + lm * 512 + (g0 >> 1);
          astore(up, p0);
          astore(up + 1, p1);
        }
      }
    }
    barrier_lgkm();
    if ((t & 7) == 7) {
      fencev();
      __syncthreads();
      if (tid == 0) astore(flags + (hid ? FLAG_H1 : FLAG_H0), (unsigned)(t + 1));
    }
  }
}

__global__ __launch_bounds__(512, 2) void k_lstm(
    const float* __restrict__ Whh0, const float* __restrict__ Wih1,
    const float* __restrict__ Whh1, const unsigned short* __restrict__ vpn,
    const int* __restrict__ eidx, const unsigned short* __restrict__ corr,
    const float* __restrict__ inith, const float* __restrict__ initc,
    unsigned* flags, unsigned* uring, unsigned* h0w, unsigned* h1w) {
  __shared__ __align__(16) short wlds[16 * 8 * 64 * 8];        // 128 KB weight tiles
  __shared__ __align__(16) unsigned short hT[16 * HST];        // 8448 B
  __shared__ __align__(16) unsigned short gbuf[8 * 4 * GST];   // 16640 B (bf16 gates)
  const int tid = threadIdx.x;
  const int bx = blockIdx.x;
  if (bx == 0)
    recur<0>(Whh0, vpn, eidx, corr, nullptr, inith, initc, flags, h0w, wlds, hT, gbuf, tid);
  else if (bx == 1)
    recur<1>(Whh1, nullptr, nullptr, nullptr, uring, inith, initc, flags, h1w, wlds, hT, gbuf, tid);
  else
    uprod(bx - 2, Wih1, flags, h0w, uring, hT, tid);
}

// ---- heads: 3x (256->512 relu ->1) via MFMA, BCE + Gaussian NLL ----
__global__ __launch_bounds__(256, 2) void k_heads(
    const unsigned short* __restrict__ h1u, const float* __restrict__ xadj,
    const float* __restrict__ lgW1, const float* __restrict__ lgb1,
    const float* __restrict__ lgW2, const float* __restrict__ lgb2,
    const float* __restrict__ muW1, const float* __restrict__ mub1,
    const float* __restrict__ muW2, const float* __restrict__ mub2,
    const float* __restrict__ vaW1, const float* __restrict__ vab1,
    const float* __restrict__ vaW2, const float* __restrict__ vab2,
    float* dout) {
  __shared__ float vals[4][3][64];
  const int tid = threadIdx.x;
  const int v = tid >> 6, l = tid & 63, lm = l & 15, lk = l >> 4;
  const int wid = blockIdx.x * 4 + v;
  const int m0 = wid * 64;

  short8 afr[4][8];
#pragma unroll
  for (int tt = 0; tt < 4; ++tt)
#pragma unroll
    for (int ks = 0; ks < 8; ++ks)
      afr[tt][ks] = *(const short8*)(h1u + (size_t)(m0 + tt * 16 + lm) * 256 + 2048 + ks * 32 + lk * 8);

  const float* W1s[3] = {lgW1, muW1, vaW1};
  const float* b1s[3] = {lgb1, mub1, vab1};
  const float* W2s[3] = {lgW2, muW2, vaW2};

  for (int h = 0; h < 3; ++h) {
    float accr[4][4];
#pragma unroll
    for (int tt = 0; tt < 4; ++tt)
#pragma unroll
      for (int r = 0; r < 4; ++r) accr[tt][r] = 0.f;
    const float* W1p = W1s[h];
    const float* b1p = b1s[h];
    const float* W2p = W2s[h];
    for (int nt = 0; nt < 32; ++nt) {
      float4e c0 = {0.f, 0.f, 0.f, 0.f}, c1 = c0, c2 = c0, c3 = c0;
      const float* wp = W1p + (size_t)(nt * 16 + lm) * 256;
#pragma unroll
      for (int ks = 0; ks < 8; ++ks) {
        short8 bfr = pack8f(wp + ks * 32 + lk * 8);
        c0 = MFMA16(afr[0][ks], bfr, c0);
        c1 = MFMA16(afr[1][ks], bfr, c1);
        c2 = MFMA16(afr[2][ks], bfr, c2);
        c3 = MFMA16(afr[3][ks], bfr, c3);
      }
      float bias = b1p[nt * 16 + lm], w2v = W2p[nt * 16 + lm];
#pragma unroll
      for (int r = 0; r < 4; ++r) {
        accr[0][r] += fmaxf(c0[r] + bias, 0.f) * w2v;
        accr[1][r] += fmaxf(c1[r] + bias, 0.f) * w2v;
        accr[2][r] += fmaxf(c2[r] + bias, 0.f) * w2v;
        accr[3][r] += fmaxf(c3[r] + bias, 0.f) * w2v;
      }
    }
#pragma unroll
    for (int tt = 0; tt < 4; ++tt)
#pragma unroll
      for (int r = 0; r < 4; ++r) {
        float a2 = accr[tt][r];
        a2 += __shfl_xor(a2, 1);
        a2 += __shfl_xor(a2, 2);
        a2 += __shfl_xor(a2, 4);
        a2 += __shfl_xor(a2, 8);
        if (lm == 0) vals[v][h][tt * 16 + lk * 4 + r] = a2;
      }
  }
  __syncthreads();
  {
    int m = m0 + l;
    int tq = m >> 3, b = m & 7;
    float z = vals[v][0][l] + lgb2[0];
    float mu = vals[v][1][l] + mub2[0];
    float lv = vals[v][2][l] + vab2[0];
    float x = xadj[(size_t)b * LSEQ + tq];
    float xt = (x > 0.f) ? 1.f : 0.f;
    float lr = fmaxf(z, 0.f) - z * xt + log1pf(expf(-fabsf(z)));
    float lw = 0.f;
    if (x > 0.f) {
      float sm = (x > 20.f) ? x : logf(expm1f(fminf(x, 20.f)));
      float d = mu - sm;
      lw = 0.5f * (lv + d * d * expf(-lv));
    }
#pragma unroll
    for (int d2 = 1; d2 < 64; d2 <<= 1) {
      lr += __shfl_xor(lr, d2);
      lw += __shfl_xor(lw, d2);
    }
    if (l == 0) {
      atomicAdd(dout + 0, lr * (1.f / 1024.f));
      atomicAdd(dout + 1, lw * (1.f / 1024.f));
    }
  }
}

extern "C" void kernel_launch(void* const* d_in, const int* in_sizes, int n_in,
                              void* d_out, int out_size, void* d_ws, size_t ws_size,
                              hipStream_t stream) {
  const float* x_adj = (const float*)d_in[0];
  const float* ee    = (const float*)d_in[1];
  const float* nemb  = (const float*)d_in[2];
  const float* ewW1  = (const float*)d_in[3];
  const float* ewb1  = (const float*)d_in[4];
  const float* ewW2  = (const float*)d_in[5];
  const float* ewb2  = (const float*)d_in[6];
  const float* Wih0  = (const float*)d_in[7];
  const float* Whh0  = (const float*)d_in[8];
  const float* Wih1  = (const float*)d_in[9];
  const float* Whh1  = (const float*)d_in[10];
  const float* muW1  = (const float*)d_in[11];
  const float* mub1  = (const float*)d_in[12];
  const float* muW2  = (const float*)d_in[13];
  const float* mub2  = (const float*)d_in[14];
  const float* vaW1  = (const float*)d_in[15];
  const float* vab1  = (const float*)d_in[16];
  const float* vaW2  = (const float*)d_in[17];
  const float* vab2  = (const float*)d_in[18];
  const float* lgW1  = (const float*)d_in[19];
  const float* lgb1  = (const float*)d_in[20];
  const float* lgW2  = (const float*)d_in[21];
  const float* lgb2  = (const float*)d_in[22];
  const float* inith = (const float*)d_in[23];
  const float* initc = (const float*)d_in[24];

  char* wsb = (char*)d_ws;
  unsigned* flags     = (unsigned*)wsb;              // spread flags, dword offsets 0/32/64/96
  unsigned* counter   = (unsigned*)(wsb + 512);
  float* P            = (float*)(wsb + WS_P);
  float* aee          = (float*)(wsb + WS_AEE);
  unsigned short* vpn = (unsigned short*)(wsb + WS_VPN);
  int* eidx           = (int*)(wsb + WS_EIDX);
  unsigned short* corr = (unsigned short*)(wsb + WS_CORR);
  unsigned* uring     = (unsigned*)(wsb + WS_URING);
  unsigned* h0w       = (unsigned*)(wsb + WS_H0);
  unsigned* h1w       = (unsigned*)(wsb + WS_H1);
  unsigned short* h0u = (unsigned short*)(wsb + WS_H0);
  unsigned short* h1u = (unsigned short*)(wsb + WS_H1);

  (void)in_sizes; (void)n_in; (void)ws_size;

  hipMemsetAsync(d_ws, 0, 4096, stream);  // flags + counter
  hipMemsetAsync(d_out, 0, (size_t)out_size * 4, stream);

  k_prep_P<<<512, 256, 0, stream>>>(Wih0, ewW2, P);
  k_prep_aee_init<<<8, 256, 0, stream>>>(Wih0, ee, ewb1, ewb2, P, inith, aee, h0u, h1u);
  k_prep_vpn<<<LSEQ, 256, 0, stream>>>(Wih0, nemb, aee, vpn);
  k_prep_eidx<<<(NB * LSEQ) / 256, 256, 0, stream>>>(x_adj, eidx, counter);
  k_prep_corr<<<NB * LSEQ, 256, 0, stream>>>(x_adj, ewW1, ewb1, P, aee, eidx, corr);
  k_lstm<<<4, 512, 0, stream>>>(Whh0, Wih1, Whh1, vpn, eidx, corr, inith, initc,
                                flags, uring, h0w, h1w);
  k_heads<<<254, 256, 0, stream>>>(h1u, x_adj, lgW1, lgb1, lgW2, lgb2,
                                   muW1, mub1, muW2, mub2, vaW1, vab1, vaW2, vab2,
                                   (float*)d_out);
}

// Round 6
// 31170.490 us; speedup vs baseline: 1.4895x; 1.4895x over previous
//
#include <hip/hip_runtime.h>

#define LSEQ 8128
#define NB 8
#define CORR_CAP 8192
#define GST 260          // gbuf row stride (shorts)
#define HST 264          // hT row stride (shorts); 528 B ≡ 16 mod 128 spreads banks
#define HROWS 9          // 8 batch rows + 1 shared zero row (lm>=8 broadcast)
#define RINGSZ 512
#define FLAG_R0 0
#define FLAG_H0 32
#define FLAG_H1 64
#define PROG_R1 96

typedef __attribute__((ext_vector_type(8))) short short8;
typedef __attribute__((ext_vector_type(4))) float float4e;

#define MFMA16(a, b, c) __builtin_amdgcn_mfma_f32_16x16x32_bf16((a), (b), (c), 0, 0, 0)

// ---- workspace layout (bytes) ----
#define WS_P      4096ul
#define WS_AEE    528384ul
#define WS_VPN    536576ul      // bf16 [8128][1024]
#define WS_EIDX   17182720ul
#define WS_CORR   17444864ul    // bf16 [8192][1024]
#define WS_URING  34222080ul    // bf16 ring [512][8][1024]
#define WS_H0     42610688ul    // bf16 [8129][8][256]
#define WS_H1     75907072ul

static __device__ __forceinline__ unsigned short f2bf(float f) {
  unsigned u = __float_as_uint(f);
  return (unsigned short)((u + 0x7fffu + ((u >> 16) & 1u)) >> 16);  // RNE
}
static __device__ __forceinline__ float blo(unsigned u) { return __uint_as_float(u << 16); }
static __device__ __forceinline__ float bhi(unsigned u) { return __uint_as_float(u & 0xffff0000u); }
static __device__ __forceinline__ unsigned addbf2(unsigned a, unsigned b) {
  float lo = blo(a) + blo(b), hi = bhi(a) + bhi(b);
  return (unsigned)f2bf(lo) | ((unsigned)f2bf(hi) << 16);
}
static __device__ __forceinline__ short8 pack8f(const float* __restrict__ p) {
  short8 r;
#pragma unroll
  for (int i = 0; i < 8; ++i) r[i] = (short)f2bf(p[i]);
  return r;
}
static __device__ __forceinline__ unsigned aload(const unsigned* p) {
  return __hip_atomic_load(p, __ATOMIC_RELAXED, __HIP_MEMORY_SCOPE_AGENT);
}
static __device__ __forceinline__ void astore(unsigned* p, unsigned v) {
  __hip_atomic_store(p, v, __ATOMIC_RELAXED, __HIP_MEMORY_SCOPE_AGENT);
}
static __device__ __forceinline__ void fencev() {
  asm volatile("s_waitcnt vmcnt(0)" ::: "memory");
}
static __device__ __forceinline__ void cbar() { asm volatile("" ::: "memory"); }
static __device__ __forceinline__ void barrier_lgkm() {
  asm volatile("s_waitcnt lgkmcnt(0)\ns_barrier" ::: "memory");
}
static __device__ __forceinline__ float sigf(float x) { return 1.f / (1.f + __expf(-x)); }
static __device__ __forceinline__ float tanhf2(float x) { return 2.f / (1.f + __expf(-2.f * x)) - 1.f; }

// ---- preps (unchanged from R5) ----
__global__ void k_prep_P(const float* __restrict__ Wih0, const float* __restrict__ ewW2,
                         float* __restrict__ P) {
  int idx = blockIdx.x * 256 + threadIdx.x;
  int g = idx >> 7, k = idx & 127;
  const float* wr = Wih0 + (size_t)g * 320 + 128;
  float s = 0.f;
#pragma unroll 8
  for (int j = 0; j < 64; ++j) s += wr[j] * ewW2[j * 128 + k];
  P[idx] = s;
}

__global__ void k_prep_aee_init(const float* __restrict__ Wih0, const float* __restrict__ ee,
                                const float* __restrict__ b1, const float* __restrict__ b2,
                                const float* __restrict__ P, const float* __restrict__ inith,
                                float* __restrict__ aee, unsigned short* __restrict__ h0u,
                                unsigned short* __restrict__ h1u) {
  int idx = blockIdx.x * 256 + threadIdx.x;  // < 2048
  int s = idx >> 10, g = idx & 1023;
  const float* wr = Wih0 + (size_t)g * 320;
  float a = 0.f;
#pragma unroll 8
  for (int i = 0; i < 128; ++i) a += wr[i] * ee[s * 128 + i];
#pragma unroll 8
  for (int j = 0; j < 64; ++j) a += wr[128 + j] * b2[j];
  const float* pr = P + (size_t)g * 128;
#pragma unroll 8
  for (int k = 0; k < 128; ++k) a += pr[k] * fmaxf(b1[k], 0.f);
  aee[s * 1024 + g] = a;
  unsigned short hv = f2bf(inith[idx & 127]);
  h0u[idx] = hv;
  h1u[idx] = hv;
}

__global__ void k_prep_vpn(const float* __restrict__ Wih0, const float* __restrict__ nemb,
                           const float* __restrict__ aee, unsigned short* __restrict__ vpn) {
  __shared__ float pn[128];
  int t = blockIdx.x, tid = threadIdx.x;
  if (tid < 32) {
    float div = expf(-9.2103403719761836f * (float)(2 * tid) / 64.f);
    float ang = (float)t * div;
    pn[2 * tid] = sinf(ang);
    pn[2 * tid + 1] = cosf(ang);
  } else if (tid < 96) {
    int r = (int)((1.f + sqrtf(8.f * (float)t + 1.f)) * 0.5f);
    while (r * (r + 1) / 2 <= t) ++r;
    while (r * (r - 1) / 2 > t) --r;
    pn[64 + (tid - 32)] = nemb[r * 64 + (tid - 32)];
  }
  __syncthreads();
#pragma unroll
  for (int rr = 0; rr < 4; ++rr) {
    int row = rr * 256 + tid;
    const float* wr = Wih0 + (size_t)row * 320 + 192;
    float s = 0.f;
#pragma unroll 8
    for (int i = 0; i < 128; ++i) s += wr[i] * pn[i];
    vpn[(size_t)t * 1024 + row] = f2bf(s + aee[row]);
  }
}

__global__ void k_prep_eidx(const float* __restrict__ xadj, int* __restrict__ eidx,
                            unsigned* __restrict__ counter) {
  int idx = blockIdx.x * 256 + threadIdx.x;
  if (idx >= NB * LSEQ) return;
  int t = idx % LSEQ;
  int e = -1;
  if (t > 0 && xadj[idx - 1] > 0.f) {
    e = (int)atomicAdd(counter, 1u);
    if (e >= CORR_CAP) e = -1;
  }
  eidx[idx] = e;
}

__global__ void k_prep_corr(const float* __restrict__ xadj, const float* __restrict__ w1,
                            const float* __restrict__ b1, const float* __restrict__ P,
                            const float* __restrict__ aee, const int* __restrict__ eidx,
                            unsigned short* __restrict__ corr) {
  __shared__ float rh[128];
  int bid = blockIdx.x;
  int e = eidx[bid];
  if (e < 0) return;
  int tid = threadIdx.x;
  float wt = xadj[bid - 1];
  if (tid < 128) {
    float bb = b1[tid];
    rh[tid] = fmaxf(wt * w1[tid] + bb, 0.f) - fmaxf(bb, 0.f);
  }
  __syncthreads();
#pragma unroll
  for (int rr = 0; rr < 4; ++rr) {
    int row = rr * 256 + tid;
    const float* pr = P + (size_t)row * 128;
    float s = 0.f;
#pragma unroll 8
    for (int k = 0; k < 128; ++k) s += pr[k] * rh[k];
    corr[(size_t)e * 1024 + row] = f2bf(s + aee[1024 + row] - aee[row]);
  }
}

// ============ persistent single-CU recurrence LSTM ============
static __device__ __forceinline__ void writeg(unsigned short* gbuf, int lm, int mt, int lk,
                                              float4e a) {
  int G = mt >> 4, jb = (mt & 15) * 16 + lk * 4;
  unsigned p0 = (unsigned)f2bf(a[0]) | ((unsigned)f2bf(a[1]) << 16);
  unsigned p1 = (unsigned)f2bf(a[2]) | ((unsigned)f2bf(a[3]) << 16);
  *(uint2*)&gbuf[(lm * 4 + G) * GST + jb] = make_uint2(p0, p1);
}

template <int LAYER>
static __device__ __forceinline__ void recur(
    const float* __restrict__ Wrec, const unsigned short* __restrict__ vpn,
    const int* __restrict__ eidx, const unsigned short* __restrict__ corr,
    const unsigned* __restrict__ uring, const float* __restrict__ inith,
    const float* __restrict__ initc, unsigned* flags, unsigned* hout,
    short* wlds, unsigned short* hT, unsigned short* gbuf, float* cbuf, int tid) {
  const int wv = tid >> 6, l = tid & 63, lm = l & 15, lk = l >> 4;
  const int lmr = (lm < 8) ? lm : 8;  // lanes 8-15 broadcast the zero row
  const int b = wv, j0 = l * 4;
  unsigned budget = 20000000u;

  for (int i = tid; i < HROWS * HST; i += 512) hT[i] = 0;
  __syncthreads();
  {
    unsigned h01 = (unsigned)f2bf(inith[j0 & 127]) | ((unsigned)f2bf(inith[(j0 + 1) & 127]) << 16);
    unsigned h23 = (unsigned)f2bf(inith[(j0 + 2) & 127]) | ((unsigned)f2bf(inith[(j0 + 3) & 127]) << 16);
    *(uint2*)&hT[b * HST + j0] = make_uint2(h01, h23);
  }
  {
    float4e ci;
#pragma unroll
    for (int r = 0; r < 4; ++r) ci[r] = initc[(j0 + r) & 127];
    *(float4e*)&cbuf[tid * 4] = ci;
  }

  // weights: 8 m-tiles/wave; tiles 0-5 in regs (192 VGPR), 6-7 in LDS
  short8 wf[6][8];
#pragma unroll
  for (int tt = 0; tt < 6; ++tt) {
    int row = (wv * 8 + tt) * 16 + lm;
#pragma unroll
    for (int ks = 0; ks < 8; ++ks)
      wf[tt][ks] = pack8f(Wrec + (size_t)row * 256 + ks * 32 + lk * 8);
  }
#pragma unroll
  for (int tt = 0; tt < 2; ++tt) {
    int row = (wv * 8 + 6 + tt) * 16 + lm, s = wv * 2 + tt;
#pragma unroll
    for (int ks = 0; ks < 8; ++ks) {
      short8 w = pack8f(Wrec + (size_t)row * 256 + ks * 32 + lk * 8);
      *(short8*)&wlds[((s * 8 + ks) * 64 + l) * 8] = w;
    }
  }
  __syncthreads();

  unsigned Tc0 = 0, Tc1 = 0;
  for (int t = 0; t < LSEQ; ++t) {
    // ---- per-step input, packed bf16 (8 VGPRs live) ----
    uint2 vv[4];
    if (LAYER == 0) {
      const uint2* vp = (const uint2*)(vpn + (size_t)t * 1024 + j0);
#pragma unroll
      for (int G = 0; G < 4; ++G) vv[G] = vp[G * 64];
      int e = eidx[b * LSEQ + t];  // wave-uniform -> scalar branch
      if (e >= 0) {
        const uint2* cp = (const uint2*)(corr + (size_t)e * 1024 + j0);
#pragma unroll
        for (int G = 0; G < 4; ++G) {
          uint2 cvv = cp[G * 64];
          vv[G].x = addbf2(vv[G].x, cvv.x);
          vv[G].y = addbf2(vv[G].y, cvv.y);
        }
      }
    } else {
      unsigned Tm = (Tc0 < Tc1) ? Tc0 : Tc1;
      while (Tm < (unsigned)(t + 1)) {
        Tc0 = aload(flags + FLAG_H0);
        Tc1 = aload(flags + FLAG_H1);
        Tm = (Tc0 < Tc1) ? Tc0 : Tc1;
        if (--budget == 0) break;
        asm volatile("s_sleep 1");
      }
      cbar();
      const unsigned* ub = uring + (size_t)(t & (RINGSZ - 1)) * 4096 + b * 512 + (j0 >> 1);
#pragma unroll
      for (int G = 0; G < 4; ++G) {
        vv[G].x = aload(ub + G * 128);
        vv[G].y = aload(ub + G * 128 + 1);
      }
    }
    // ---- MFMA phase: gates_rec = Wrec @ h(t-1) ----
    short8 bfr[8];
#pragma unroll
    for (int ks = 0; ks < 8; ++ks)
      bfr[ks] = *(const short8*)(hT + lmr * HST + ks * 32 + lk * 8);
#pragma unroll
    for (int tp = 0; tp < 3; ++tp) {
      float4e a0 = {0.f, 0.f, 0.f, 0.f}, a1 = {0.f, 0.f, 0.f, 0.f};
#pragma unroll
      for (int ks = 0; ks < 8; ++ks) {
        a0 = MFMA16(wf[2 * tp][ks], bfr[ks], a0);
        a1 = MFMA16(wf[2 * tp + 1][ks], bfr[ks], a1);
      }
      if (lm < 8) {
        writeg(gbuf, lm, wv * 8 + 2 * tp, lk, a0);
        writeg(gbuf, lm, wv * 8 + 2 * tp + 1, lk, a1);
      }
    }
    {
      float4e a0 = {0.f, 0.f, 0.f, 0.f}, a1 = {0.f, 0.f, 0.f, 0.f};
      int s0 = wv * 2, s1 = s0 + 1;
#pragma unroll
      for (int ks = 0; ks < 8; ++ks) {
        short8 w0 = *(const short8*)&wlds[((s0 * 8 + ks) * 64 + l) * 8];
        short8 w1 = *(const short8*)&wlds[((s1 * 8 + ks) * 64 + l) * 8];
        a0 = MFMA16(w0, bfr[ks], a0);
        a1 = MFMA16(w1, bfr[ks], a1);
      }
      if (lm < 8) {
        writeg(gbuf, lm, wv * 8 + 6, lk, a0);
        writeg(gbuf, lm, wv * 8 + 7, lk, a1);
      }
    }
    barrier_lgkm();
    // ---- update: thread owns (b=wv, j0..j0+3); c lives in LDS ----
    {
      float4e cc = *(const float4e*)&cbuf[tid * 4];
      float gt[4][4];
#pragma unroll
      for (int G = 0; G < 4; ++G) {
        uint2 gv = *(const uint2*)&gbuf[(b * 4 + G) * GST + j0];
        gt[G][0] = blo(gv.x) + blo(vv[G].x);
        gt[G][1] = bhi(gv.x) + bhi(vv[G].x);
        gt[G][2] = blo(gv.y) + blo(vv[G].y);
        gt[G][3] = bhi(gv.y) + bhi(vv[G].y);
      }
      float hv[4];
#pragma unroll
      for (int r = 0; r < 4; ++r) {
        float cn = sigf(gt[1][r]) * cc[r] + sigf(gt[0][r]) * tanhf2(gt[2][r]);
        cc[r] = cn;
        hv[r] = sigf(gt[3][r]) * tanhf2(cn);
      }
      *(float4e*)&cbuf[tid * 4] = cc;
      unsigned h01 = (unsigned)f2bf(hv[0]) | ((unsigned)f2bf(hv[1]) << 16);
      unsigned h23 = (unsigned)f2bf(hv[2]) | ((unsigned)f2bf(hv[3]) << 16);
      *(uint2*)&hT[b * HST + j0] = make_uint2(h01, h23);
      unsigned* hp = hout + (size_t)(t + 1) * 1024 + b * 128 + (j0 >> 1);
      astore(hp, h01);
      astore(hp + 1, h23);
    }
    barrier_lgkm();
    if (LAYER == 0) {
      if ((t & 7) == 7) {
        fencev();
        __syncthreads();
        if (tid == 0) astore(flags + FLAG_R0, (unsigned)(t + 1));
      }
    } else {
      if ((t & 63) == 63 && tid == 0) astore(flags + PROG_R1, (unsigned)(t + 1));
    }
  }
}

static __device__ __forceinline__ void uprod(
    int hid, const float* __restrict__ Wih1, unsigned* flags,
    const unsigned* __restrict__ h0w, unsigned* uring, unsigned short* hB, int tid) {
  const int wv = tid >> 6, l = tid & 63, lm = l & 15, lk = l >> 4;
  const int lmr = (lm < 8) ? lm : 8;
  unsigned budget = 20000000u;
  for (int i = tid; i < HROWS * HST; i += 512) hB[i] = 0;
  short8 wf[4][8];
#pragma unroll
  for (int tt = 0; tt < 4; ++tt) {
    int row = hid * 512 + (wv * 4 + tt) * 16 + lm;
#pragma unroll
    for (int ks = 0; ks < 8; ++ks)
      wf[tt][ks] = pack8f(Wih1 + (size_t)row * 256 + ks * 32 + lk * 8);
  }
  __syncthreads();
  unsigned Fc = 0, Pc = 0;
  // preload h0(0) (slot 1)
  while (Fc < 1u) {
    Fc = aload(flags + FLAG_R0);
    if (--budget == 0) break;
    asm volatile("s_sleep 1");
  }
  cbar();
  uint2 hw = ((const uint2*)(h0w + (size_t)1 * 1024))[tid];
  for (int t = 0; t < LSEQ; ++t) {
    int d = tid * 2;
    *(uint2*)((unsigned*)hB + (d >> 7) * (HST / 2) + (d & 127)) = hw;
    barrier_lgkm();
    // prefetch h0(t+1) (slot t+2) while MFMAs run
    if (t + 1 < LSEQ) {
      while (Fc < (unsigned)(t + 2)) {
        Fc = aload(flags + FLAG_R0);
        if (--budget == 0) break;
        asm volatile("s_sleep 1");
      }
      while ((unsigned)(t + 1) >= Pc + 448u) {  // ring back-pressure
        Pc = aload(flags + PROG_R1);
        if (--budget == 0) break;
        asm volatile("s_sleep 1");
      }
      cbar();
      hw = ((const uint2*)(h0w + (size_t)(t + 2) * 1024))[tid];
    }
    short8 bfr[8];
#pragma unroll
    for (int ks = 0; ks < 8; ++ks)
      bfr[ks] = *(const short8*)(hB + lmr * HST + ks * 32 + lk * 8);
    int slot = t & (RINGSZ - 1);
#pragma unroll
    for (int tp = 0; tp < 2; ++tp) {
      float4e a0 = {0.f, 0.f, 0.f, 0.f}, a1 = {0.f, 0.f, 0.f, 0.f};
#pragma unroll
      for (int ks = 0; ks < 8; ++ks) {
        a0 = MFMA16(wf[2 * tp][ks], bfr[ks], a0);
        a1 = MFMA16(wf[2 * tp + 1][ks], bfr[ks], a1);
      }
      if (lm < 8) {
#pragma unroll
        for (int q = 0; q < 2; ++q) {
          float4e a = q ? a1 : a0;
          int g0 = hid * 512 + (wv * 4 + 2 * tp + q) * 16 + lk * 4;
          unsigned p0 = (unsigned)f2bf(a[0]) | ((unsigned)f2bf(a[1]) << 16);
          unsigned p1 = (unsigned)f2bf(a[2]) | ((unsigned)f2bf(a[3]) << 16);
          unsigned* up = uring + (size_t)slot * 4096 + lm * 512 + (g0 >> 1);
          astore(up, p0);
          astore(up + 1, p1);
        }
      }
    }
    barrier_lgkm();
    if ((t & 7) == 7) {
      fencev();
      __syncthreads();
      if (tid == 0) astore(flags + (hid ? FLAG_H1 : FLAG_H0), (unsigned)(t + 1));
    }
  }
}

__global__ __launch_bounds__(512, 1) void k_lstm(
    const float* __restrict__ Whh0, const float* __restrict__ Wih1,
    const float* __restrict__ Whh1, const unsigned short* __restrict__ vpn,
    const int* __restrict__ eidx, const unsigned short* __restrict__ corr,
    const float* __restrict__ inith, const float* __restrict__ initc,
    unsigned* flags, unsigned* uring, unsigned* h0w, unsigned* h1w) {
  __shared__ __align__(16) short wlds[16 * 8 * 64 * 8];        // 131072 B
  __shared__ __align__(16) unsigned short hT[HROWS * HST];     // 4752 B
  __shared__ __align__(16) unsigned short gbuf[8 * 4 * GST];   // 16640 B
  __shared__ __align__(16) float cbuf[512 * 4];                // 8192 B -> 160656 total
  const int tid = threadIdx.x;
  const int bx = blockIdx.x;
  if (bx == 0)
    recur<0>(Whh0, vpn, eidx, corr, nullptr, inith, initc, flags, h0w, wlds, hT, gbuf, cbuf, tid);
  else if (bx == 1)
    recur<1>(Whh1, nullptr, nullptr, nullptr, uring, inith, initc, flags, h1w, wlds, hT, gbuf, cbuf, tid);
  else
    uprod(bx - 2, Wih1, flags, h0w, uring, hT, tid);
}

// ---- heads (unchanged) ----
__global__ __launch_bounds__(256, 2) void k_heads(
    const unsigned short* __restrict__ h1u, const float* __restrict__ xadj,
    const float* __restrict__ lgW1, const float* __restrict__ lgb1,
    const float* __restrict__ lgW2, const float* __restrict__ lgb2,
    const float* __restrict__ muW1, const float* __restrict__ mub1,
    const float* __restrict__ muW2, const float* __restrict__ mub2,
    const float* __restrict__ vaW1, const float* __restrict__ vab1,
    const float* __restrict__ vaW2, const float* __restrict__ vab2,
    float* dout) {
  __shared__ float vals[4][3][64];
  const int tid = threadIdx.x;
  const int v = tid >> 6, l = tid & 63, lm = l & 15, lk = l >> 4;
  const int wid = blockIdx.x * 4 + v;
  const int m0 = wid * 64;

  short8 afr[4][8];
#pragma unroll
  for (int tt = 0; tt < 4; ++tt)
#pragma unroll
    for (int ks = 0; ks < 8; ++ks)
      afr[tt][ks] = *(const short8*)(h1u + (size_t)(m0 + tt * 16 + lm) * 256 + 2048 + ks * 32 + lk * 8);

  const float* W1s[3] = {lgW1, muW1, vaW1};
  const float* b1s[3] = {lgb1, mub1, vab1};
  const float* W2s[3] = {lgW2, muW2, vaW2};

  for (int h = 0; h < 3; ++h) {
    float accr[4][4];
#pragma unroll
    for (int tt = 0; tt < 4; ++tt)
#pragma unroll
      for (int r = 0; r < 4; ++r) accr[tt][r] = 0.f;
    const float* W1p = W1s[h];
    const float* b1p = b1s[h];
    const float* W2p = W2s[h];
    for (int nt = 0; nt < 32; ++nt) {
      float4e c0 = {0.f, 0.f, 0.f, 0.f}, c1 = c0, c2 = c0, c3 = c0;
      const float* wp = W1p + (size_t)(nt * 16 + lm) * 256;
#pragma unroll
      for (int ks = 0; ks < 8; ++ks) {
        short8 bfr = pack8f(wp + ks * 32 + lk * 8);
        c0 = MFMA16(afr[0][ks], bfr, c0);
        c1 = MFMA16(afr[1][ks], bfr, c1);
        c2 = MFMA16(afr[2][ks], bfr, c2);
        c3 = MFMA16(afr[3][ks], bfr, c3);
      }
      float bias = b1p[nt * 16 + lm], w2v = W2p[nt * 16 + lm];
#pragma unroll
      for (int r = 0; r < 4; ++r) {
        accr[0][r] += fmaxf(c0[r] + bias, 0.f) * w2v;
        accr[1][r] += fmaxf(c1[r] + bias, 0.f) * w2v;
        accr[2][r] += fmaxf(c2[r] + bias, 0.f) * w2v;
        accr[3][r] += fmaxf(c3[r] + bias, 0.f) * w2v;
      }
    }
#pragma unroll
    for (int tt = 0; tt < 4; ++tt)
#pragma unroll
      for (int r = 0; r < 4; ++r) {
        float a2 = accr[tt][r];
        a2 += __shfl_xor(a2, 1);
        a2 += __shfl_xor(a2, 2);
        a2 += __shfl_xor(a2, 4);
        a2 += __shfl_xor(a2, 8);
        if (lm == 0) vals[v][h][tt * 16 + lk * 4 + r] = a2;
      }
  }
  __syncthreads();
  {
    int m = m0 + l;
    int tq = m >> 3, b = m & 7;
    float z = vals[v][0][l] + lgb2[0];
    float mu = vals[v][1][l] + mub2[0];
    float lv = vals[v][2][l] + vab2[0];
    float x = xadj[(size_t)b * LSEQ + tq];
    float xt = (x > 0.f) ? 1.f : 0.f;
    float lr = fmaxf(z, 0.f) - z * xt + log1pf(expf(-fabsf(z)));
    float lw = 0.f;
    if (x > 0.f) {
      float sm = (x > 20.f) ? x : logf(expm1f(fminf(x, 20.f)));
      float d = mu - sm;
      lw = 0.5f * (lv + d * d * expf(-lv));
    }
#pragma unroll
    for (int d2 = 1; d2 < 64; d2 <<= 1) {
      lr += __shfl_xor(lr, d2);
      lw += __shfl_xor(lw, d2);
    }
    if (l == 0) {
      atomicAdd(dout + 0, lr * (1.f / 1024.f));
      atomicAdd(dout + 1, lw * (1.f / 1024.f));
    }
  }
}

extern "C" void kernel_launch(void* const* d_in, const int* in_sizes, int n_in,
                              void* d_out, int out_size, void* d_ws, size_t ws_size,
                              hipStream_t stream) {
  const float* x_adj = (const float*)d_in[0];
  const float* ee    = (const float*)d_in[1];
  const float* nemb  = (const float*)d_in[2];
  const float* ewW1  = (const float*)d_in[3];
  const float* ewb1  = (const float*)d_in[4];
  const float* ewW2  = (const float*)d_in[5];
  const float* ewb2  = (const float*)d_in[6];
  const float* Wih0  = (const float*)d_in[7];
  const float* Whh0  = (const float*)d_in[8];
  const float* Wih1  = (const float*)d_in[9];
  const float* Whh1  = (const float*)d_in[10];
  const float* muW1  = (const float*)d_in[11];
  const float* mub1  = (const float*)d_in[12];
  const float* muW2  = (const float*)d_in[13];
  const float* mub2  = (const float*)d_in[14];
  const float* vaW1  = (const float*)d_in[15];
  const float* vab1  = (const float*)d_in[16];
  const float* vaW2  = (const float*)d_in[17];
  const float* vab2  = (const float*)d_in[18];
  const float* lgW1  = (const float*)d_in[19];
  const float* lgb1  = (const float*)d_in[20];
  const float* lgW2  = (const float*)d_in[21];
  const float* lgb2  = (const float*)d_in[22];
  const float* inith = (const float*)d_in[23];
  const float* initc = (const float*)d_in[24];

  char* wsb = (char*)d_ws;
  unsigned* flags      = (unsigned*)wsb;
  unsigned* counter    = (unsigned*)(wsb + 512);
  float* P             = (float*)(wsb + WS_P);
  float* aee           = (float*)(wsb + WS_AEE);
  unsigned short* vpn  = (unsigned short*)(wsb + WS_VPN);
  int* eidx            = (int*)(wsb + WS_EIDX);
  unsigned short* corr = (unsigned short*)(wsb + WS_CORR);
  unsigned* uring      = (unsigned*)(wsb + WS_URING);
  unsigned* h0w        = (unsigned*)(wsb + WS_H0);
  unsigned* h1w        = (unsigned*)(wsb + WS_H1);
  unsigned short* h0u  = (unsigned short*)(wsb + WS_H0);
  unsigned short* h1u  = (unsigned short*)(wsb + WS_H1);

  (void)in_sizes; (void)n_in; (void)ws_size;

  hipMemsetAsync(d_ws, 0, 4096, stream);
  hipMemsetAsync(d_out, 0, (size_t)out_size * 4, stream);

  k_prep_P<<<512, 256, 0, stream>>>(Wih0, ewW2, P);
  k_prep_aee_init<<<8, 256, 0, stream>>>(Wih0, ee, ewb1, ewb2, P, inith, aee, h0u, h1u);
  k_prep_vpn<<<LSEQ, 256, 0, stream>>>(Wih0, nemb, aee, vpn);
  k_prep_eidx<<<(NB * LSEQ) / 256, 256, 0, stream>>>(x_adj, eidx, counter);
  k_prep_corr<<<NB * LSEQ, 256, 0, stream>>>(x_adj, ewW1, ewb1, P, aee, eidx, corr);
  k_lstm<<<4, 512, 0, stream>>>(Whh0, Wih1, Whh1, vpn, eidx, corr, inith, initc,
                                flags, uring, h0w, h1w);
  k_heads<<<254, 256, 0, stream>>>(h1u, x_adj, lgW1, lgb1, lgW2, lgb2,
                                   muW1, mub1, muW2, mub2, vaW1, vab1, vaW2, vab2,
                                   (float*)d_out);
}